// Round 13
// baseline (621.422 us; speedup 1.0000x reference)
//
#include <hip/hip_runtime.h>
#include <cstdint>
#include <cmath>

typedef unsigned short u16;
typedef unsigned int   u32;

using bf16x8 = __attribute__((ext_vector_type(8))) short;
using f32x4  = __attribute__((ext_vector_type(4))) float;

#define DM 256        // d_model
#define W0 448        // layer-0 input width padded 392 -> 448 (multiple of 64)
#define W0_REAL 392

__device__ __forceinline__ float bf2f(u16 v) {
  union { u32 u; float f; } c; c.u = ((u32)v) << 16; return c.f;
}
__device__ __forceinline__ u16 f2bf(float f) {   // cold-path scalar convert (RNE)
  union { float f; u32 u; } c; c.f = f;
  u32 u = c.u;
  return (u16)((u + 0x7FFFu + ((u >> 16) & 1u)) >> 16);
}
// HW packed convert: 2 f32 -> packed 2x bf16 (RNE), single VALU instruction
__device__ __forceinline__ u32 cvtpk(float lo, float hi) {
  u32 r;
  asm("v_cvt_pk_bf16_f32 %0, %1, %2" : "=v"(r) : "v"(lo), "v"(hi));
  return r;
}
__device__ __forceinline__ u16 f2bf_hw(float f) { return (u16)cvtpk(f, f); }
__device__ __forceinline__ float siluf(float y) {
  return y / (1.0f + __expf(-y));
}
__device__ __forceinline__ uint4 pack8(float f0, float f1, float f2, float f3,
                                       float f4, float f5, float f6, float f7) {
  uint4 o;
  o.x = cvtpk(f0, f1);
  o.y = cvtpk(f2, f3);
  o.z = cvtpk(f4, f5);
  o.w = cvtpk(f6, f7);
  return o;
}
// acc += relu(bf16x8(hv) + e[0..7]) elementwise
__device__ __forceinline__ void acc8(float4& lo, float4& hi, uint4 hv,
                                     float4 ea, float4 eb) {
  lo.x += fmaxf(bf2f((u16)(hv.x & 0xFFFF)) + ea.x, 0.f);
  lo.y += fmaxf(bf2f((u16)(hv.x >> 16))    + ea.y, 0.f);
  lo.z += fmaxf(bf2f((u16)(hv.y & 0xFFFF)) + ea.z, 0.f);
  lo.w += fmaxf(bf2f((u16)(hv.y >> 16))    + ea.w, 0.f);
  hi.x += fmaxf(bf2f((u16)(hv.z & 0xFFFF)) + eb.x, 0.f);
  hi.y += fmaxf(bf2f((u16)(hv.z >> 16))    + eb.y, 0.f);
  hi.z += fmaxf(bf2f((u16)(hv.w & 0xFFFF)) + eb.z, 0.f);
  hi.w += fmaxf(bf2f((u16)(hv.w >> 16))    + eb.w, 0.f);
}

// ================================================================================
// setup_a: merged independent precompute — prep_weights | t_table | cproj | ef_tab
// ================================================================================
__global__ void setup_a(const float* __restrict__ conv0_W1,
                        const float* __restrict__ conv0_W2,
                        const float* __restrict__ convs_W1,
                        const float* __restrict__ convs_W2,
                        const float* __restrict__ atomW,
                        const float* __restrict__ bondW,
                        u16* __restrict__ w10t, u16* __restrict__ w20t,
                        u16* __restrict__ wc1t, u16* __restrict__ wc2t,
                        u16* __restrict__ wht,
                        const float* __restrict__ t_W1, const float* __restrict__ t_b1,
                        const float* __restrict__ t_W2, const float* __restrict__ t_b2,
                        float* __restrict__ ttab,
                        const float* __restrict__ cv, const float* __restrict__ cond_W,
                        const float* __restrict__ cond_b, float* __restrict__ cprojb, int B,
                        const float* __restrict__ bond_emb, const float* __restrict__ emask_emb,
                        const float* __restrict__ edge_W1, const float* __restrict__ edge_b1,
                        const float* __restrict__ edge_W2, const float* __restrict__ edge_b2,
                        float* __restrict__ eftab,
                        int PN, int CP) {
  __shared__ float sm[256];
  __shared__ float sm2[256];
  int b = blockIdx.x;
  int t = threadIdx.x;

  if (b < PN) {
    // ---- prep_weights (round-8 mapping) ----
    int idx = b * 256 + t;
    const int s0 = DM * W0;        // 114688
    const int s1 = 5 * DM * DM;    // 327680 (wc1t, row-major transposed)
    const int s2 = DM * DM;        // 65536  (w20t, frag-major)
    const int s3 = 5 * DM * DM;    // 327680 (wc2t, frag-major)
    const int s4 = 32 * DM;        // 8192   (wht)
    if (idx < s0) {
      int n = idx / W0, k = idx - n * W0;
      w10t[idx] = f2bf((k < W0_REAL) ? conv0_W1[(size_t)k * DM + n] : 0.f);
      return;
    }
    idx -= s0;
    if (idx < s1) {
      int m = idx >> 16, r = idx & 65535, n = r >> 8, k = r & 255;
      wc1t[idx] = f2bf(convs_W1[(size_t)m * 65536 + k * DM + n]);
      return;
    }
    idx -= s1;
    if (idx < s2) {
      int j = idx & 7, lane = (idx >> 3) & 63, kk = (idx >> 9) & 7;
      int nt = (idx >> 12) & 7, wn = (idx >> 15) & 1;
      int n = wn * 128 + nt * 16 + (lane & 15);
      int k = kk * 32 + (lane >> 4) * 8 + j;
      w20t[idx] = f2bf(conv0_W2[(size_t)k * DM + n]);
      return;
    }
    idx -= s2;
    if (idx < s3) {
      int m = idx >> 16, r = idx & 65535;
      int j = r & 7, lane = (r >> 3) & 63, kk = (r >> 9) & 7;
      int nt = (r >> 12) & 7, wn = (r >> 15) & 1;
      int n = wn * 128 + nt * 16 + (lane & 15);
      int k = kk * 32 + (lane >> 4) * 8 + j;
      wc2t[idx] = f2bf(convs_W2[(size_t)m * 65536 + k * DM + n]);
      return;
    }
    idx -= s3;
    if (idx < s4) {
      int j = idx >> 8, k = idx & 255;
      float v = 0.0f;
      if (j < 16) v = atomW[k * 16 + j];
      else if (j < 21) v = bondW[k * 5 + (j - 16)];
      wht[idx] = f2bf(v);
    }
    return;
  }
  b -= PN;
  if (b < 200) {
    // ---- t_table: row b ----
    float tv = (float)b;
    float coef = -logf(10000.0f) / 127.0f;
    int j = t & 127;
    float ang = tv * expf(coef * (float)j);
    sm[t] = (t < 128) ? sinf(ang) : cosf(ang);
    __syncthreads();
    float acc = t_b1[t];
    for (int k = 0; k < 256; ++k) acc = fmaf(sm[k], t_W1[k * 256 + t], acc);
    sm2[t] = acc / (1.0f + expf(-acc));
    __syncthreads();
    float acc2 = t_b2[t];
    for (int k = 0; k < 256; ++k) acc2 = fmaf(sm2[k], t_W2[k * 256 + t], acc2);
    ttab[b * 256 + t] = acc2;
    return;
  }
  b -= 200;
  if (b < CP) {
    // ---- cond projection ----
    int i = b * 256 + t;
    if (i < B * 256) {
      int g = i >> 8, c = i & 255;
      cprojb[i] = fmaf(cv[g * 2], cond_W[c], fmaf(cv[g * 2 + 1], cond_W[256 + c], cond_b[c]));
    }
    return;
  }
  b -= CP;
  {
    // ---- ef_tab: bidx = b in 0..9 ----
    int bt = b >> 1, m = b & 1;
    if (t < 64) sm[t] = bond_emb[bt * 64 + t];
    else if (t < 72) sm[t] = emask_emb[m * 8 + (t - 64)];
    __syncthreads();
    float acc = edge_b1[t];
    for (int k = 0; k < 72; ++k) acc = fmaf(sm[k], edge_W1[k * 256 + t], acc);
    sm2[t] = acc / (1.0f + expf(-acc));
    __syncthreads();
    float acc2 = edge_b2[t];
    for (int k = 0; k < 256; ++k) acc2 = fmaf(sm2[k], edge_W2[k * 256 + t], acc2);
    eftab[b * 256 + t] = acc2;
  }
}

// ================================================================================
// setup_b: merged second stage — h0 build (wave-per-node) | e0_tab | deg
// ================================================================================
__global__ __launch_bounds__(256) void setup_b(
    const int* __restrict__ x, const int* __restrict__ nm,
    const int* __restrict__ tnode, const int* __restrict__ batch,
    const float* __restrict__ atom_emb, const float* __restrict__ nmask_emb,
    const float* __restrict__ ttab, const float* __restrict__ cproj,
    u16* __restrict__ h0, int N,
    const float* __restrict__ eftab, const float* __restrict__ e0W,
    float* __restrict__ e0tab,
    const int* __restrict__ dst, int* __restrict__ deg, int E,
    int HB, int DB) {
  __shared__ float ef[256];
  int b = blockIdx.x;
  int t = threadIdx.x;

  if (b < HB) {
    // ---- h0 build: wave-per-node, grid-stride ----
    int wid = t >> 6, lane = t & 63;
    int nwaves = HB * 4;
    for (int n = b * 4 + wid; n < N; n += nwaves) {
      int xv = x[n], nmv = nm[n], tv = tnode[n], bv = batch[n];  // wave-uniform
      uint4 o = make_uint4(0, 0, 0, 0);
      if (lane < 16) {
        const float* s = atom_emb + (size_t)xv * 128 + lane * 8;
        float4 a = *(const float4*)s, bb = *(const float4*)(s + 4);
        o = pack8(a.x, a.y, a.z, a.w, bb.x, bb.y, bb.z, bb.w);
      } else if (lane == 16) {
        const float* s = nmask_emb + (size_t)nmv * 8;
        float4 a = *(const float4*)s, bb = *(const float4*)(s + 4);
        o = pack8(a.x, a.y, a.z, a.w, bb.x, bb.y, bb.z, bb.w);
      } else if (lane < 49) {
        int cc = lane * 8 - 136;
        const float* ta = ttab + (size_t)tv * 256 + cc;
        const float* cb = cproj + (size_t)bv * 256 + cc;
        float4 a = *(const float4*)ta, bb = *(const float4*)(ta + 4);
        float4 c = *(const float4*)cb, d = *(const float4*)(cb + 4);
        o = pack8(a.x + c.x, a.y + c.y, a.z + c.z, a.w + c.w,
                  bb.x + d.x, bb.y + d.y, bb.z + d.z, bb.w + d.w);
      }
      if (lane < 56)
        *(uint4*)(h0 + (size_t)n * W0 + lane * 8) = o;
    }
    return;
  }
  b -= HB;
  if (b < 10) {
    // ---- e0_tab (256 threads, 2 cols per thread) ----
    ef[t] = eftab[b * 256 + t];
    __syncthreads();
    for (int c = t; c < W0; c += 256) {
      float acc = 0.0f;
      if (c < W0_REAL) {
        for (int k = 0; k < 256; ++k) acc = fmaf(ef[k], e0W[k * W0_REAL + c], acc);
      }
      e0tab[b * W0 + c] = acc;
    }
    return;
  }
  b -= 10;
  {
    // ---- deg: grid-stride ----
    int stride = DB * 256;
    for (int e = b * 256 + t; e < E; e += stride)
      atomicAdd(&deg[dst[e]], 1);
  }
}

// ---------------- CSR build ----------------------------------------------------
__global__ void scan1_kernel(const int* __restrict__ deg, int* __restrict__ ro,
                             int* __restrict__ bsum, int N) {
  __shared__ int tmp[256];
  int tid = threadIdx.x, i = blockIdx.x * 256 + tid;
  int v = (i < N) ? deg[i] : 0;
  tmp[tid] = v;
  __syncthreads();
  for (int o = 1; o < 256; o <<= 1) {
    int t = (tid >= o) ? tmp[tid - o] : 0;
    __syncthreads();
    tmp[tid] += t;
    __syncthreads();
  }
  if (i < N) ro[i] = tmp[tid] - v;
  if (tid == 255) bsum[blockIdx.x] = tmp[255];
}

__global__ void scan2_kernel(int* __restrict__ bsum, int nb) {
  __shared__ int tmp[256];
  int tid = threadIdx.x;
  int v = (tid < nb) ? bsum[tid] : 0;
  tmp[tid] = v;
  __syncthreads();
  for (int o = 1; o < 256; o <<= 1) {
    int t = (tid >= o) ? tmp[tid - o] : 0;
    __syncthreads();
    tmp[tid] += t;
    __syncthreads();
  }
  if (tid < nb) bsum[tid] = tmp[tid] - v;
}

__global__ void scan3_kernel(int* __restrict__ ro, int* __restrict__ cur,
                             const int* __restrict__ bsum, int N, int E) {
  int i = blockIdx.x * 256 + threadIdx.x;
  if (i < N) {
    int r = ro[i] + bsum[blockIdx.x];
    ro[i] = r;
    cur[i] = r;
  }
  if (i == 0) ro[N] = E;
}

__global__ void fill_kernel(const int* __restrict__ src, const int* __restrict__ dst,
                            const int* __restrict__ ea, const int* __restrict__ em,
                            int* __restrict__ cur, int* __restrict__ csr, int E) {
  int e = blockIdx.x * 256 + threadIdx.x;
  if (e < E) {
    int d = dst[e];
    int pos = atomicAdd(&cur[d], 1);
    csr[pos] = src[e] | ((ea[e] * 2 + em[e]) << 20);
  }
}

// ---------------- agg (W=256): 2 edges per wave, lane owns 8 cols --------------
__global__ __launch_bounds__(256) void agg_z256(
    const u16* __restrict__ h, const float* __restrict__ etab,
    const int* __restrict__ ro, const int* __restrict__ csr,
    const float* __restrict__ epsp, u16* __restrict__ z, int N) {
  int wid = threadIdx.x >> 6, lane = threadIdx.x & 63;
  int n = blockIdx.x * 4 + wid;
  if (n >= N) return;
  int s0 = ro[n], s1 = ro[n + 1];
  float eps1 = 1.0f + *epsp;
  int half = lane >> 5, li = lane & 31;
  int c8 = li * 8;
  float4 aLo = {0, 0, 0, 0}, aHi = {0, 0, 0, 0};

  for (int base = s0; base < s1; base += 64) {
    int m = s1 - base; if (m > 64) m = 64;
    int pk = (lane < m) ? csr[base + lane] : 0;
    int j = 0;
    for (; j + 3 < m; j += 4) {       // 4 edges per iter (2 per half-wave pair)
      int p0 = __shfl(pk, j + half);
      int p1 = __shfl(pk, j + 2 + half);
      uint4 h0v = *(const uint4*)(h + (size_t)(p0 & 0xFFFFF) * 256 + c8);
      uint4 h1v = *(const uint4*)(h + (size_t)(p1 & 0xFFFFF) * 256 + c8);
      const float* e0p = etab + (size_t)(p0 >> 20) * 256 + c8;
      const float* e1p = etab + (size_t)(p1 >> 20) * 256 + c8;
      float4 e0a = *(const float4*)e0p, e0b = *(const float4*)(e0p + 4);
      float4 e1a = *(const float4*)e1p, e1b = *(const float4*)(e1p + 4);
      acc8(aLo, aHi, h0v, e0a, e0b);
      acc8(aLo, aHi, h1v, e1a, e1b);
    }
    for (; j < m; j += 2) {           // tail (up to 3 edges)
      int idx = j + half;
      bool act = idx < m;
      int p = __shfl(pk, act ? idx : (m - 1));
      uint4 hv = *(const uint4*)(h + (size_t)(p & 0xFFFFF) * 256 + c8);
      const float* ep = etab + (size_t)(p >> 20) * 256 + c8;
      float4 ea = *(const float4*)ep, eb = *(const float4*)(ep + 4);
      if (act) acc8(aLo, aHi, hv, ea, eb);
    }
  }
  // fold half-1 partial sums into half-0
  aLo.x += __shfl(aLo.x, li + 32); aLo.y += __shfl(aLo.y, li + 32);
  aLo.z += __shfl(aLo.z, li + 32); aLo.w += __shfl(aLo.w, li + 32);
  aHi.x += __shfl(aHi.x, li + 32); aHi.y += __shfl(aHi.y, li + 32);
  aHi.z += __shfl(aHi.z, li + 32); aHi.w += __shfl(aHi.w, li + 32);
  if (half == 0) {
    uint4 hn = *(const uint4*)(h + (size_t)n * 256 + c8);
    uint4 o = pack8(
        eps1 * bf2f((u16)(hn.x & 0xFFFF)) + aLo.x,
        eps1 * bf2f((u16)(hn.x >> 16))    + aLo.y,
        eps1 * bf2f((u16)(hn.y & 0xFFFF)) + aLo.z,
        eps1 * bf2f((u16)(hn.y >> 16))    + aLo.w,
        eps1 * bf2f((u16)(hn.z & 0xFFFF)) + aHi.x,
        eps1 * bf2f((u16)(hn.z >> 16))    + aHi.y,
        eps1 * bf2f((u16)(hn.w & 0xFFFF)) + aHi.z,
        eps1 * bf2f((u16)(hn.w >> 16))    + aHi.w);
    *(uint4*)(z + (size_t)n * 256 + c8) = o;
  }
}

// ---------------- agg (W=448, layer 0): lane owns 8 cols, 56 live lanes --------
__global__ __launch_bounds__(256) void agg_z448(
    const u16* __restrict__ h, const float* __restrict__ etab,
    const int* __restrict__ ro, const int* __restrict__ csr,
    const float* __restrict__ epsp, u16* __restrict__ z, int N) {
  int wid = threadIdx.x >> 6, lane = threadIdx.x & 63;
  int n = blockIdx.x * 4 + wid;
  if (n >= N) return;
  int s0 = ro[n], s1 = ro[n + 1];
  float eps1 = 1.0f + *epsp;
  bool live = lane < 56;
  int c8 = live ? lane * 8 : 440;    // clamp dead lanes to a harmless chunk
  float4 aLo = {0, 0, 0, 0}, aHi = {0, 0, 0, 0};

  for (int base = s0; base < s1; base += 64) {
    int m = s1 - base; if (m > 64) m = 64;
    int pk = (lane < m) ? csr[base + lane] : 0;
    int j = 0;
    for (; j + 1 < m; j += 2) {
      int p0 = __shfl(pk, j);
      int p1 = __shfl(pk, j + 1);
      uint4 h0v = *(const uint4*)(h + (size_t)(p0 & 0xFFFFF) * W0 + c8);
      uint4 h1v = *(const uint4*)(h + (size_t)(p1 & 0xFFFFF) * W0 + c8);
      const float* e0p = etab + (size_t)(p0 >> 20) * W0 + c8;
      const float* e1p = etab + (size_t)(p1 >> 20) * W0 + c8;
      float4 e0a = *(const float4*)e0p, e0b = *(const float4*)(e0p + 4);
      float4 e1a = *(const float4*)e1p, e1b = *(const float4*)(e1p + 4);
      acc8(aLo, aHi, h0v, e0a, e0b);
      acc8(aLo, aHi, h1v, e1a, e1b);
    }
    if (j < m) {
      int p = __shfl(pk, j);
      uint4 hv = *(const uint4*)(h + (size_t)(p & 0xFFFFF) * W0 + c8);
      const float* ep = etab + (size_t)(p >> 20) * W0 + c8;
      float4 ea = *(const float4*)ep, eb = *(const float4*)(ep + 4);
      acc8(aLo, aHi, hv, ea, eb);
    }
  }
  if (live) {
    uint4 hn = *(const uint4*)(h + (size_t)n * W0 + c8);
    uint4 o = pack8(
        eps1 * bf2f((u16)(hn.x & 0xFFFF)) + aLo.x,
        eps1 * bf2f((u16)(hn.x >> 16))    + aLo.y,
        eps1 * bf2f((u16)(hn.y & 0xFFFF)) + aLo.z,
        eps1 * bf2f((u16)(hn.y >> 16))    + aLo.w,
        eps1 * bf2f((u16)(hn.z & 0xFFFF)) + aHi.x,
        eps1 * bf2f((u16)(hn.z >> 16))    + aHi.y,
        eps1 * bf2f((u16)(hn.w & 0xFFFF)) + aHi.z,
        eps1 * bf2f((u16)(hn.w >> 16))    + aHi.w);
    *(uint4*)(z + (size_t)n * W0 + c8) = o;
  }
}

// ---------------- fused 2-stage MLP: C = silu(BN(silu(A@W1+b1)@W2+b2)) ---------
// Round-8/10 verified config: 128x256 tile, 256 thr / 4 waves (2x2 grid), 64KB
// LDS, launch_bounds(256,2) (no reg-cap spill), K=32 dbuf staging, frag-major W2.
__device__ __forceinline__ void g2l16(const u16* g, u16* l) {
  __builtin_amdgcn_global_load_lds(
      (__attribute__((address_space(1))) u32*)g,
      (__attribute__((address_space(3))) u32*)l, 16, 0, 0);
}

__global__ __launch_bounds__(256, 2) void layer_mlp(
    const u16* __restrict__ A, const u16* __restrict__ B1T,
    const float* __restrict__ b1v,
    const u16* __restrict__ B2F, const float* __restrict__ b2v,
    const float* __restrict__ gamma, const float* __restrict__ beta,
    u16* __restrict__ C, int M, int K1) {
  __shared__ __align__(16) u16 smem[32768];   // 64 KB: dbuf staging 2x24KB / U 64KB
  int tid = threadIdx.x;
  int wid = tid >> 6, lane = tid & 63;
  int q = lane >> 4, rr = lane & 15;
  int wm = wid >> 1, wn = wid & 1;          // 2x2 wave grid
  int m0 = blockIdx.x * 128;
  int lr2 = lane >> 2;                      // row within a 16-row DMA group
  int swz2 = (lane & 3) ^ ((lr2 >> 1) & 3); // swizzled 16B k-chunk this lane fetches

  f32x4 acc[4][8] = {};
  const int nk = K1 >> 5;                   // K-step = 32

  // ---- prologue: stage K-step 0 into buf0 ----
#pragma unroll
  for (int p = 0; p < 2; ++p) {             // A: 128 rows -> 8 groups of 16
    int g = wid * 2 + p;
    int gr = m0 + g * 16 + lr2; if (gr >= M) gr = M - 1;
    g2l16(A + (size_t)gr * K1 + swz2 * 8, smem + g * 512);
  }
#pragma unroll
  for (int p = 0; p < 4; ++p) {             // B: 256 rows -> 16 groups of 16
    int g = wid * 4 + p;
    g2l16(B1T + (size_t)(g * 16 + lr2) * K1 + swz2 * 8, smem + 4096 + g * 512);
  }
  __syncthreads();

  // ---- stage 1 main loop: stage(next) || compute(cur) ----
  for (int k = 0; k < nk; ++k) {
    int cur = (k & 1) * 12288;
    if (k + 1 < nk) {
      int nxt = 12288 - cur;
      int k0 = (k + 1) << 5;
#pragma unroll
      for (int p = 0; p < 2; ++p) {
        int g = wid * 2 + p;
        int gr = m0 + g * 16 + lr2; if (gr >= M) gr = M - 1;
        g2l16(A + (size_t)gr * K1 + k0 + swz2 * 8, smem + nxt + g * 512);
      }
#pragma unroll
      for (int p = 0; p < 4; ++p) {
        int g = wid * 4 + p;
        g2l16(B1T + (size_t)(g * 16 + lr2) * K1 + k0 + swz2 * 8,
              smem + nxt + 4096 + g * 512);
      }
    }
    const u16* dA = smem + cur;             // 128 rows x 32 k
    const u16* dB = smem + cur + 4096;      // 256 rows x 32 k
    int slot = (q ^ ((rr >> 1) & 3)) << 3;  // matches write-side swz2 key
    bf16x8 af[4], bf[8];
#pragma unroll
    for (int mt = 0; mt < 4; ++mt)
      af[mt] = *(const bf16x8*)&dA[(wm * 64 + mt * 16 + rr) * 32 + slot];
#pragma unroll
    for (int nt = 0; nt < 8; ++nt)
      bf[nt] = *(const bf16x8*)&dB[(wn * 128 + nt * 16 + rr) * 32 + slot];
#pragma unroll
    for (int mt = 0; mt < 4; ++mt)
#pragma unroll
      for (int nt = 0; nt < 8; ++nt)
        acc[mt][nt] = __builtin_amdgcn_mfma_f32_16x16x32_bf16(af[mt], bf[nt], acc[mt][nt], 0, 0, 0);
    __syncthreads();
  }

  // ---- epilogue 1: U = silu(acc + b1) -> swizzled LDS [128][256] bf16 ----
  // element (row,col) lives at u16 index row*256 + (((col>>3)^(row&7))<<3)+(col&7)
#pragma unroll
  for (int nt = 0; nt < 8; ++nt) {
    int col = wn * 128 + nt * 16 + rr;
    float bb = b1v[col];
    int cc = col >> 3, cl = col & 7;
#pragma unroll
    for (int mt = 0; mt < 4; ++mt)
#pragma unroll
      for (int i = 0; i < 4; ++i) {
        int row = wm * 64 + mt * 16 + q * 4 + i;
        smem[row * 256 + ((cc ^ (row & 7)) << 3) + cl] =
            f2bf_hw(siluf(acc[mt][nt][i] + bb));
      }
  }
  __syncthreads();

  // ---- stage 2: acc = U[128x256] @ W2; U from LDS, W2 frag-major coalesced ----
#pragma unroll
  for (int mt = 0; mt < 4; ++mt)
#pragma unroll
    for (int nt = 0; nt < 8; ++nt)
      acc[mt][nt] = (f32x4){0.f, 0.f, 0.f, 0.f};
  const u16* bbase = B2F + ((size_t)wn << 15) + (lane << 3);
#pragma unroll 2
  for (int kk = 0; kk < 8; ++kk) {
    bf16x8 af[4], bf[8];
#pragma unroll
    for (int mt = 0; mt < 4; ++mt)
      af[mt] = *(const bf16x8*)&smem[(wm * 64 + mt * 16 + rr) * 256 +
                                     ((((kk << 2) | q) ^ (rr & 7)) << 3)];
#pragma unroll
    for (int nt = 0; nt < 8; ++nt)
      bf[nt] = *(const bf16x8*)(bbase + ((nt << 12) | (kk << 9)));
#pragma unroll
    for (int mt = 0; mt < 4; ++mt)
#pragma unroll
      for (int nt = 0; nt < 8; ++nt)
        acc[mt][nt] = __builtin_amdgcn_mfma_f32_16x16x32_bf16(af[mt], bf[nt], acc[mt][nt], 0, 0, 0);
  }
  __syncthreads();                          // all waves done reading U

  // ---- epilogue 2: bias/BN/SiLU -> per-wave 16KB LDS slice -> coalesced store
  u16* slice = smem + wid * 8192;
#pragma unroll
  for (int nt = 0; nt < 8; ++nt) {
    int c = wn * 128 + nt * 16 + rr;
    float b = b2v[c];
    float sc = gamma ? gamma[c] * 0.9999950000374997f : 1.0f;   // gamma/sqrt(1+1e-5)
    float sh = beta ? beta[c] : 0.0f;
#pragma unroll
    for (int mt = 0; mt < 4; ++mt)
#pragma unroll
      for (int i = 0; i < 4; ++i) {
        float y = (acc[mt][nt][i] + b) * sc + sh;
        slice[(mt * 16 + q * 4 + i) * 128 + nt * 16 + rr] = f2bf_hw(siluf(y));
      }
  }
  __syncthreads();
  int rbase = m0 + wm * 64;
  int cbase = wn * 128;
#pragma unroll
  for (int j = 0; j < 16; ++j) {
    int idx = j * 64 + lane;                // uint4 index in slice (1024 total)
    int rloc = idx >> 4;                    // 16 uint4 per 128-col row
    int c8 = (idx & 15) * 8;
    if (rbase + rloc < M)
      *(uint4*)(C + (size_t)(rbase + rloc) * 256 + cbase + c8) =
          *(const uint4*)(slice + rloc * 128 + c8);
  }
}

// ---------------- MFMA head GEMM: [N,256] @ [256,32] -> atom_out[N,16], P[N,8(5)]
__global__ __launch_bounds__(256) void head_gemm(
    const u16* __restrict__ A, const u16* __restrict__ WT,
    const float* __restrict__ atomB,
    float* __restrict__ atom_out, float* __restrict__ P, int M) {
  __shared__ __align__(16) u16 lA[128 * 32];
  __shared__ __align__(16) u16 lB[32 * 264];
  int tid = threadIdx.x;
  int wid = tid >> 6, lane = tid & 63;
  int q = lane >> 4, rr = lane & 15;
  int m0 = blockIdx.x * 128;

  for (int i = tid; i < 32 * 256; i += 256)
    lB[(i >> 8) * 264 + (i & 255)] = WT[i];

  f32x4 acc[2][2] = {};
  int arow = tid >> 2, acol = (tid & 3) * 8;

  for (int k0 = 0; k0 < 256; k0 += 32) {
#pragma unroll
    for (int p = 0; p < 2; ++p) {
      int gr = m0 + p * 64 + arow;
      if (gr >= M) gr = M - 1;
      g2l16(A + (size_t)gr * 256 + k0 + acol, &lA[p * 2048 + wid * 512]);
    }
    __syncthreads();
    bf16x8 af[2], bfr[2];
#pragma unroll
    for (int mt = 0; mt < 2; ++mt)
      af[mt] = *(const bf16x8*)&lA[(wid * 32 + mt * 16 + rr) * 32 + q * 8];
#pragma unroll
    for (int nt = 0; nt < 2; ++nt)
      bfr[nt] = *(const bf16x8*)&lB[(nt * 16 + rr) * 264 + k0 + q * 8];
#pragma unroll
    for (int mt = 0; mt < 2; ++mt)
#pragma unroll
      for (int nt = 0; nt < 2; ++nt)
        acc[mt][nt] = __builtin_amdgcn_mfma_f32_16x16x32_bf16(af[mt], bfr[nt], acc[mt][nt], 0, 0, 0);
    __syncthreads();
  }

#pragma unroll
  for (int nt = 0; nt < 2; ++nt) {
    int c = nt * 16 + rr;
    float bb = (c < 16) ? atomB[c] : 0.0f;
#pragma unroll
    for (int mt = 0; mt < 2; ++mt) {
      int rbase = m0 + wid * 32 + mt * 16 + q * 4;
#pragma unroll
      for (int r2 = 0; r2 < 4; ++r2) {
        int row = rbase + r2;
        if (row < M) {
          float v = acc[mt][nt][r2];
          if (c < 16) atom_out[(size_t)row * 16 + c] = v + bb;
          else if (c < 21) P[(size_t)row * 8 + (c - 16)] = v;
        }
      }
    }
  }
}

// ---------------- bond edge output: out[e] = P[src]+P[dst]+b -------------------
__global__ __launch_bounds__(256) void bond_edge(
    const float* __restrict__ P, const int* __restrict__ src,
    const int* __restrict__ dst, const float* __restrict__ b,
    float* __restrict__ out, int E) {
  __shared__ float so[256 * 5];
  int t = threadIdx.x;
  int e = blockIdx.x * 256 + t;
  float v0 = 0, v1 = 0, v2 = 0, v3 = 0, v4 = 0;
  if (e < E) {
    int s = src[e], d = dst[e];
    float4 ps = *(const float4*)(P + (size_t)s * 8);
    float  p4s = P[(size_t)s * 8 + 4];
    float4 pd = *(const float4*)(P + (size_t)d * 8);
    float  p4d = P[(size_t)d * 8 + 4];
    v0 = ps.x + pd.x + b[0];
    v1 = ps.y + pd.y + b[1];
    v2 = ps.z + pd.z + b[2];
    v3 = ps.w + pd.w + b[3];
    v4 = p4s + p4d + b[4];
  }
  so[t * 5 + 0] = v0; so[t * 5 + 1] = v1; so[t * 5 + 2] = v2;
  so[t * 5 + 3] = v3; so[t * 5 + 4] = v4;
  __syncthreads();
  size_t base = (size_t)blockIdx.x * 256 * 5;
  size_t lim = (size_t)E * 5;
  for (int i = t; i < 256 * 5; i += 256) {
    size_t g = base + i;
    if (g < lim) out[g] = so[i];
  }
}

// ---------------- host ---------------------------------------------------------
extern "C" void kernel_launch(void* const* d_in, const int* in_sizes, int n_in,
                              void* d_out, int out_size, void* d_ws, size_t ws_size,
                              hipStream_t stream) {
  const int*   x_noisy   = (const int*)d_in[0];
  const int*   nmaskobs  = (const int*)d_in[1];
  const int*   ea        = (const int*)d_in[2];
  const int*   em        = (const int*)d_in[3];
  const int*   eidx      = (const int*)d_in[4];
  const int*   tnode     = (const int*)d_in[5];
  const float* cvec      = (const float*)d_in[6];
  const int*   batch     = (const int*)d_in[7];
  const float* atom_emb  = (const float*)d_in[8];
  const float* bond_emb  = (const float*)d_in[9];
  const float* nmask_emb = (const float*)d_in[10];
  const float* emask_emb = (const float*)d_in[11];
  const float* t_W1      = (const float*)d_in[12];
  const float* t_b1      = (const float*)d_in[13];
  const float* t_W2      = (const float*)d_in[14];
  const float* t_b2      = (const float*)d_in[15];
  const float* cond_W    = (const float*)d_in[16];
  const float* cond_b    = (const float*)d_in[17];
  const float* edge_W1   = (const float*)d_in[18];
  const float* edge_b1   = (const float*)d_in[19];
  const float* edge_W2   = (const float*)d_in[20];
  const float* edge_b2   = (const float*)d_in[21];
  const float* e0_W      = (const float*)d_in[22];
  const float* conv0_W1  = (const float*)d_in[23];
  const float* conv0_b1  = (const float*)d_in[24];
  const float* conv0_W2  = (const float*)d_in[25];
  const float* conv0_b2  = (const float*)d_in[26];
  const float* conv0_eps = (const float*)d_in[27];
  const float* convs_W1  = (const float*)d_in[28];
  const float* convs_b1  = (const float*)d_in[29];
  const float* convs_W2  = (const float*)d_in[30];
  const float* convs_b2  = (const float*)d_in[31];
  const float* convs_eps = (const float*)d_in[32];
  const float* bn_gamma  = (const float*)d_in[33];
  const float* bn_beta   = (const float*)d_in[34];
  const float* atom_W    = (const float*)d_in[35];
  const float* atom_b    = (const float*)d_in[36];
  const float* bond_W    = (const float*)d_in[37];
  const float* bond_b    = (const float*)d_in[38];

  const int N = in_sizes[0];
  const int E = in_sizes[2];
  const int B = in_sizes[6] / 2;
  const int* srcp = eidx;
  const int* dstp = eidx + E;

  char* base = (char*)d_ws;
  size_t off = 0;
  auto alloc = [&](size_t bytes) -> char* {
    char* p = base + off;
    off = (off + bytes + 255) & ~(size_t)255;
    return p;
  };
  u16* h0   = (u16*)alloc((size_t)N * W0 * 2);     // reused as h [N,256] ping
  u16* z0   = (u16*)alloc((size_t)N * W0 * 2);     // reused as z [N,256]
  u16* w10t = (u16*)alloc((size_t)DM * W0 * 2);
  u16* w20t = (u16*)alloc((size_t)DM * DM * 2);    // frag-major
  u16* wc1t = (u16*)alloc((size_t)5 * DM * DM * 2);
  u16* wc2t = (u16*)alloc((size_t)5 * DM * DM * 2); // frag-major
  u16* wht  = (u16*)alloc((size_t)32 * DM * 2);
  float* ttab  = (float*)alloc((size_t)200 * DM * 4);
  float* cprojb= (float*)alloc((size_t)B * DM * 4);
  float* eftab = (float*)alloc((size_t)10 * DM * 4);
  float* e0tab = (float*)alloc((size_t)10 * W0 * 4);
  float* Pbuf  = (float*)alloc((size_t)N * 8 * 4);
  int* deg  = (int*)alloc((size_t)N * 4);
  int* ro   = (int*)alloc((size_t)(N + 1) * 4);
  int* cur  = (int*)alloc((size_t)N * 4);
  int* csr  = (int*)alloc((size_t)E * 4);
  int* bsum = (int*)alloc((size_t)256 * 4);
  (void)ws_size; (void)n_in; (void)out_size;

  u16* hbuf = h0;
  u16* zbuf = z0;
  float* atom_out = (float*)d_out;
  float* bond_out = atom_out + (size_t)N * 16;

  hipMemsetAsync(deg, 0, (size_t)N * 4, stream);

  // ---- setup launch 1: weights + tables (all independent) ----
  const int prep_tot = DM * W0 + 5 * DM * DM + DM * DM + 5 * DM * DM + 32 * DM;
  const int PN = (prep_tot + 255) / 256;
  const int CP = (B * DM + 255) / 256;
  setup_a<<<PN + 200 + CP + 10, 256, 0, stream>>>(
      conv0_W1, conv0_W2, convs_W1, convs_W2, atom_W, bond_W,
      w10t, w20t, wc1t, wc2t, wht,
      t_W1, t_b1, t_W2, t_b2, ttab,
      cvec, cond_W, cond_b, cprojb, B,
      bond_emb, emask_emb, edge_W1, edge_b1, edge_W2, edge_b2, eftab,
      PN, CP);

  // ---- setup launch 2: h0 (wave-per-node) + e0tab + deg (grid-stride) ----
  const int HB = 2048;
  const int DB = 256;
  setup_b<<<HB + 10 + DB, 256, 0, stream>>>(
      x_noisy, nmaskobs, tnode, batch, atom_emb, nmask_emb, ttab, cprojb, h0, N,
      eftab, e0_W, e0tab,
      dstp, deg, E, HB, DB);

  // ---- CSR chain ----
  const int nscan = (N + 255) / 256;
  scan1_kernel<<<nscan, 256, 0, stream>>>(deg, ro, bsum, N);
  scan2_kernel<<<1, 256, 0, stream>>>(bsum, nscan);
  scan3_kernel<<<nscan, 256, 0, stream>>>(ro, cur, bsum, N, E);
  fill_kernel<<<(E + 255) / 256, 256, 0, stream>>>(srcp, dstp, ea, em, cur, csr, E);

  const int ggrid = (N + 127) / 128;  // 128-row tiles, 391 blocks
  const int nagg = (N + 3) / 4;
  // layer 0
  agg_z448<<<nagg, 256, 0, stream>>>(h0, e0tab, ro, csr, conv0_eps, z0, N);
  layer_mlp<<<ggrid, 256, 0, stream>>>(z0, w10t, conv0_b1, w20t, conv0_b2,
                                       bn_gamma, bn_beta, hbuf, N, W0);
  // layers 1..5
  for (int i = 0; i < 5; ++i) {
    agg_z256<<<nagg, 256, 0, stream>>>(hbuf, eftab, ro, csr, convs_eps + i, zbuf, N);
    layer_mlp<<<ggrid, 256, 0, stream>>>(zbuf, wc1t + (size_t)i * DM * DM, convs_b1 + i * DM,
                                         wc2t + (size_t)i * DM * DM, convs_b2 + i * DM,
                                         bn_gamma + (i + 1) * DM, bn_beta + (i + 1) * DM,
                                         hbuf, N, DM);
  }
  // heads
  head_gemm<<<(N + 127) / 128, 256, 0, stream>>>(hbuf, wht, atom_b, atom_out, Pbuf, N);
  bond_edge<<<(E + 255) / 256, 256, 0, stream>>>(Pbuf, srcp, dstp, bond_b, bond_out, E);
}

// Round 14
// 604.791 us; speedup vs baseline: 1.0275x; 1.0275x over previous
//
#include <hip/hip_runtime.h>
#include <cstdint>
#include <cmath>

typedef unsigned short u16;
typedef unsigned int   u32;

using bf16x8 = __attribute__((ext_vector_type(8))) short;
using f32x4  = __attribute__((ext_vector_type(4))) float;

#define DM 256        // d_model
#define W0 448        // layer-0 input width padded 392 -> 448 (multiple of 64)
#define W0_REAL 392

__device__ __forceinline__ float bf2f(u16 v) {
  union { u32 u; float f; } c; c.u = ((u32)v) << 16; return c.f;
}
__device__ __forceinline__ u16 f2bf(float f) {   // cold-path scalar convert (RNE)
  union { float f; u32 u; } c; c.f = f;
  u32 u = c.u;
  return (u16)((u + 0x7FFFu + ((u >> 16) & 1u)) >> 16);
}
// HW packed convert: 2 f32 -> packed 2x bf16 (RNE), single VALU instruction
__device__ __forceinline__ u32 cvtpk(float lo, float hi) {
  u32 r;
  asm("v_cvt_pk_bf16_f32 %0, %1, %2" : "=v"(r) : "v"(lo), "v"(hi));
  return r;
}
__device__ __forceinline__ u16 f2bf_hw(float f) { return (u16)cvtpk(f, f); }
__device__ __forceinline__ float siluf(float y) {
  return y / (1.0f + __expf(-y));
}
__device__ __forceinline__ uint4 pack8(float f0, float f1, float f2, float f3,
                                       float f4, float f5, float f6, float f7) {
  uint4 o;
  o.x = cvtpk(f0, f1);
  o.y = cvtpk(f2, f3);
  o.z = cvtpk(f4, f5);
  o.w = cvtpk(f6, f7);
  return o;
}
// acc += relu(bf16x8(hv) + e[0..7]) elementwise
__device__ __forceinline__ void acc8(float4& lo, float4& hi, uint4 hv,
                                     float4 ea, float4 eb) {
  lo.x += fmaxf(bf2f((u16)(hv.x & 0xFFFF)) + ea.x, 0.f);
  lo.y += fmaxf(bf2f((u16)(hv.x >> 16))    + ea.y, 0.f);
  lo.z += fmaxf(bf2f((u16)(hv.y & 0xFFFF)) + ea.z, 0.f);
  lo.w += fmaxf(bf2f((u16)(hv.y >> 16))    + ea.w, 0.f);
  hi.x += fmaxf(bf2f((u16)(hv.z & 0xFFFF)) + eb.x, 0.f);
  hi.y += fmaxf(bf2f((u16)(hv.z >> 16))    + eb.y, 0.f);
  hi.z += fmaxf(bf2f((u16)(hv.w & 0xFFFF)) + eb.z, 0.f);
  hi.w += fmaxf(bf2f((u16)(hv.w >> 16))    + eb.w, 0.f);
}

// ================================================================================
// setup_a: merged independent precompute — prep_weights | t_table | cproj | ef_tab
// ================================================================================
__global__ void setup_a(const float* __restrict__ conv0_W1,
                        const float* __restrict__ conv0_W2,
                        const float* __restrict__ convs_W1,
                        const float* __restrict__ convs_W2,
                        const float* __restrict__ atomW,
                        const float* __restrict__ bondW,
                        u16* __restrict__ w10t, u16* __restrict__ w20t,
                        u16* __restrict__ wc1t, u16* __restrict__ wc2t,
                        u16* __restrict__ wht,
                        const float* __restrict__ t_W1, const float* __restrict__ t_b1,
                        const float* __restrict__ t_W2, const float* __restrict__ t_b2,
                        float* __restrict__ ttab,
                        const float* __restrict__ cv, const float* __restrict__ cond_W,
                        const float* __restrict__ cond_b, float* __restrict__ cprojb, int B,
                        const float* __restrict__ bond_emb, const float* __restrict__ emask_emb,
                        const float* __restrict__ edge_W1, const float* __restrict__ edge_b1,
                        const float* __restrict__ edge_W2, const float* __restrict__ edge_b2,
                        float* __restrict__ eftab,
                        int PN, int CP) {
  __shared__ float sm[256];
  __shared__ float sm2[256];
  int b = blockIdx.x;
  int t = threadIdx.x;

  if (b < PN) {
    // ---- prep_weights (round-8 mapping) ----
    int idx = b * 256 + t;
    const int s0 = DM * W0;        // 114688
    const int s1 = 5 * DM * DM;    // 327680 (wc1t, row-major transposed)
    const int s2 = DM * DM;        // 65536  (w20t, frag-major)
    const int s3 = 5 * DM * DM;    // 327680 (wc2t, frag-major)
    const int s4 = 32 * DM;        // 8192   (wht)
    if (idx < s0) {
      int n = idx / W0, k = idx - n * W0;
      w10t[idx] = f2bf((k < W0_REAL) ? conv0_W1[(size_t)k * DM + n] : 0.f);
      return;
    }
    idx -= s0;
    if (idx < s1) {
      int m = idx >> 16, r = idx & 65535, n = r >> 8, k = r & 255;
      wc1t[idx] = f2bf(convs_W1[(size_t)m * 65536 + k * DM + n]);
      return;
    }
    idx -= s1;
    if (idx < s2) {
      int j = idx & 7, lane = (idx >> 3) & 63, kk = (idx >> 9) & 7;
      int nt = (idx >> 12) & 7, wn = (idx >> 15) & 1;
      int n = wn * 128 + nt * 16 + (lane & 15);
      int k = kk * 32 + (lane >> 4) * 8 + j;
      w20t[idx] = f2bf(conv0_W2[(size_t)k * DM + n]);
      return;
    }
    idx -= s2;
    if (idx < s3) {
      int m = idx >> 16, r = idx & 65535;
      int j = r & 7, lane = (r >> 3) & 63, kk = (r >> 9) & 7;
      int nt = (r >> 12) & 7, wn = (r >> 15) & 1;
      int n = wn * 128 + nt * 16 + (lane & 15);
      int k = kk * 32 + (lane >> 4) * 8 + j;
      wc2t[idx] = f2bf(convs_W2[(size_t)m * 65536 + k * DM + n]);
      return;
    }
    idx -= s3;
    if (idx < s4) {
      int j = idx >> 8, k = idx & 255;
      float v = 0.0f;
      if (j < 16) v = atomW[k * 16 + j];
      else if (j < 21) v = bondW[k * 5 + (j - 16)];
      wht[idx] = f2bf(v);
    }
    return;
  }
  b -= PN;
  if (b < 200) {
    // ---- t_table: row b ----
    float tv = (float)b;
    float coef = -logf(10000.0f) / 127.0f;
    int j = t & 127;
    float ang = tv * expf(coef * (float)j);
    sm[t] = (t < 128) ? sinf(ang) : cosf(ang);
    __syncthreads();
    float acc = t_b1[t];
    for (int k = 0; k < 256; ++k) acc = fmaf(sm[k], t_W1[k * 256 + t], acc);
    sm2[t] = acc / (1.0f + expf(-acc));
    __syncthreads();
    float acc2 = t_b2[t];
    for (int k = 0; k < 256; ++k) acc2 = fmaf(sm2[k], t_W2[k * 256 + t], acc2);
    ttab[b * 256 + t] = acc2;
    return;
  }
  b -= 200;
  if (b < CP) {
    // ---- cond projection ----
    int i = b * 256 + t;
    if (i < B * 256) {
      int g = i >> 8, c = i & 255;
      cprojb[i] = fmaf(cv[g * 2], cond_W[c], fmaf(cv[g * 2 + 1], cond_W[256 + c], cond_b[c]));
    }
    return;
  }
  b -= CP;
  {
    // ---- ef_tab: bidx = b in 0..9 ----
    int bt = b >> 1, m = b & 1;
    if (t < 64) sm[t] = bond_emb[bt * 64 + t];
    else if (t < 72) sm[t] = emask_emb[m * 8 + (t - 64)];
    __syncthreads();
    float acc = edge_b1[t];
    for (int k = 0; k < 72; ++k) acc = fmaf(sm[k], edge_W1[k * 256 + t], acc);
    sm2[t] = acc / (1.0f + expf(-acc));
    __syncthreads();
    float acc2 = edge_b2[t];
    for (int k = 0; k < 256; ++k) acc2 = fmaf(sm2[k], edge_W2[k * 256 + t], acc2);
    eftab[b * 256 + t] = acc2;
  }
}

// ================================================================================
// setup_b: merged second stage — h0 build (wave-per-node) | e0_tab | deg
// ================================================================================
__global__ __launch_bounds__(256) void setup_b(
    const int* __restrict__ x, const int* __restrict__ nm,
    const int* __restrict__ tnode, const int* __restrict__ batch,
    const float* __restrict__ atom_emb, const float* __restrict__ nmask_emb,
    const float* __restrict__ ttab, const float* __restrict__ cproj,
    u16* __restrict__ h0, int N,
    const float* __restrict__ eftab, const float* __restrict__ e0W,
    float* __restrict__ e0tab,
    const int* __restrict__ dst, int* __restrict__ deg, int E,
    int HB, int DB) {
  __shared__ float ef[256];
  int b = blockIdx.x;
  int t = threadIdx.x;

  if (b < HB) {
    // ---- h0 build: wave-per-node, grid-stride ----
    int wid = t >> 6, lane = t & 63;
    int nwaves = HB * 4;
    for (int n = b * 4 + wid; n < N; n += nwaves) {
      int xv = x[n], nmv = nm[n], tv = tnode[n], bv = batch[n];  // wave-uniform
      uint4 o = make_uint4(0, 0, 0, 0);
      if (lane < 16) {
        const float* s = atom_emb + (size_t)xv * 128 + lane * 8;
        float4 a = *(const float4*)s, bb = *(const float4*)(s + 4);
        o = pack8(a.x, a.y, a.z, a.w, bb.x, bb.y, bb.z, bb.w);
      } else if (lane == 16) {
        const float* s = nmask_emb + (size_t)nmv * 8;
        float4 a = *(const float4*)s, bb = *(const float4*)(s + 4);
        o = pack8(a.x, a.y, a.z, a.w, bb.x, bb.y, bb.z, bb.w);
      } else if (lane < 49) {
        int cc = lane * 8 - 136;
        const float* ta = ttab + (size_t)tv * 256 + cc;
        const float* cb = cproj + (size_t)bv * 256 + cc;
        float4 a = *(const float4*)ta, bb = *(const float4*)(ta + 4);
        float4 c = *(const float4*)cb, d = *(const float4*)(cb + 4);
        o = pack8(a.x + c.x, a.y + c.y, a.z + c.z, a.w + c.w,
                  bb.x + d.x, bb.y + d.y, bb.z + d.z, bb.w + d.w);
      }
      if (lane < 56)
        *(uint4*)(h0 + (size_t)n * W0 + lane * 8) = o;
    }
    return;
  }
  b -= HB;
  if (b < 10) {
    // ---- e0_tab (256 threads, 2 cols per thread) ----
    ef[t] = eftab[b * 256 + t];
    __syncthreads();
    for (int c = t; c < W0; c += 256) {
      float acc = 0.0f;
      if (c < W0_REAL) {
        for (int k = 0; k < 256; ++k) acc = fmaf(ef[k], e0W[k * W0_REAL + c], acc);
      }
      e0tab[b * W0 + c] = acc;
    }
    return;
  }
  b -= 10;
  {
    // ---- deg: grid-stride ----
    int stride = DB * 256;
    for (int e = b * 256 + t; e < E; e += stride)
      atomicAdd(&deg[dst[e]], 1);
  }
}

// ---------------- CSR build ----------------------------------------------------
__global__ void scan1_kernel(const int* __restrict__ deg, int* __restrict__ ro,
                             int* __restrict__ bsum, int N) {
  __shared__ int tmp[256];
  int tid = threadIdx.x, i = blockIdx.x * 256 + tid;
  int v = (i < N) ? deg[i] : 0;
  tmp[tid] = v;
  __syncthreads();
  for (int o = 1; o < 256; o <<= 1) {
    int t = (tid >= o) ? tmp[tid - o] : 0;
    __syncthreads();
    tmp[tid] += t;
    __syncthreads();
  }
  if (i < N) ro[i] = tmp[tid] - v;
  if (tid == 255) bsum[blockIdx.x] = tmp[255];
}

__global__ void scan2_kernel(int* __restrict__ bsum, int nb) {
  __shared__ int tmp[256];
  int tid = threadIdx.x;
  int v = (tid < nb) ? bsum[tid] : 0;
  tmp[tid] = v;
  __syncthreads();
  for (int o = 1; o < 256; o <<= 1) {
    int t = (tid >= o) ? tmp[tid - o] : 0;
    __syncthreads();
    tmp[tid] += t;
    __syncthreads();
  }
  if (tid < nb) bsum[tid] = tmp[tid] - v;
}

__global__ void scan3_kernel(int* __restrict__ ro, int* __restrict__ cur,
                             const int* __restrict__ bsum, int N, int E) {
  int i = blockIdx.x * 256 + threadIdx.x;
  if (i < N) {
    int r = ro[i] + bsum[blockIdx.x];
    ro[i] = r;
    cur[i] = r;
  }
  if (i == 0) ro[N] = E;
}

__global__ void fill_kernel(const int* __restrict__ src, const int* __restrict__ dst,
                            const int* __restrict__ ea, const int* __restrict__ em,
                            int* __restrict__ cur, int* __restrict__ csr, int E) {
  int e = blockIdx.x * 256 + threadIdx.x;
  if (e < E) {
    int d = dst[e];
    int pos = atomicAdd(&cur[d], 1);
    csr[pos] = src[e] | ((ea[e] * 2 + em[e]) << 20);
  }
}

// ---------------- agg (W=256): 2 edges per wave, lane owns 8 cols --------------
// Own-row h[n] load hoisted BEFORE the edge loop: independent address known at
// entry -> overlaps its ~500-900cy latency with the gather phase instead of
// serializing at the tail.
__global__ __launch_bounds__(256) void agg_z256(
    const u16* __restrict__ h, const float* __restrict__ etab,
    const int* __restrict__ ro, const int* __restrict__ csr,
    const float* __restrict__ epsp, u16* __restrict__ z, int N) {
  int wid = threadIdx.x >> 6, lane = threadIdx.x & 63;
  int n = blockIdx.x * 4 + wid;
  if (n >= N) return;
  int s0 = ro[n], s1 = ro[n + 1];
  float eps1 = 1.0f + *epsp;
  int half = lane >> 5, li = lane & 31;
  int c8 = li * 8;
  uint4 hn = *(const uint4*)(h + (size_t)n * 256 + c8);   // issued early
  float4 aLo = {0, 0, 0, 0}, aHi = {0, 0, 0, 0};

  for (int base = s0; base < s1; base += 64) {
    int m = s1 - base; if (m > 64) m = 64;
    int pk = (lane < m) ? csr[base + lane] : 0;
    int j = 0;
    for (; j + 3 < m; j += 4) {       // 4 edges per iter (2 per half-wave pair)
      int p0 = __shfl(pk, j + half);
      int p1 = __shfl(pk, j + 2 + half);
      uint4 h0v = *(const uint4*)(h + (size_t)(p0 & 0xFFFFF) * 256 + c8);
      uint4 h1v = *(const uint4*)(h + (size_t)(p1 & 0xFFFFF) * 256 + c8);
      const float* e0p = etab + (size_t)(p0 >> 20) * 256 + c8;
      const float* e1p = etab + (size_t)(p1 >> 20) * 256 + c8;
      float4 e0a = *(const float4*)e0p, e0b = *(const float4*)(e0p + 4);
      float4 e1a = *(const float4*)e1p, e1b = *(const float4*)(e1p + 4);
      acc8(aLo, aHi, h0v, e0a, e0b);
      acc8(aLo, aHi, h1v, e1a, e1b);
    }
    for (; j < m; j += 2) {           // tail (up to 3 edges)
      int idx = j + half;
      bool act = idx < m;
      int p = __shfl(pk, act ? idx : (m - 1));
      uint4 hv = *(const uint4*)(h + (size_t)(p & 0xFFFFF) * 256 + c8);
      const float* ep = etab + (size_t)(p >> 20) * 256 + c8;
      float4 ea = *(const float4*)ep, eb = *(const float4*)(ep + 4);
      if (act) acc8(aLo, aHi, hv, ea, eb);
    }
  }
  // fold half-1 partial sums into half-0
  aLo.x += __shfl(aLo.x, li + 32); aLo.y += __shfl(aLo.y, li + 32);
  aLo.z += __shfl(aLo.z, li + 32); aLo.w += __shfl(aLo.w, li + 32);
  aHi.x += __shfl(aHi.x, li + 32); aHi.y += __shfl(aHi.y, li + 32);
  aHi.z += __shfl(aHi.z, li + 32); aHi.w += __shfl(aHi.w, li + 32);
  if (half == 0) {
    uint4 o = pack8(
        eps1 * bf2f((u16)(hn.x & 0xFFFF)) + aLo.x,
        eps1 * bf2f((u16)(hn.x >> 16))    + aLo.y,
        eps1 * bf2f((u16)(hn.y & 0xFFFF)) + aLo.z,
        eps1 * bf2f((u16)(hn.y >> 16))    + aLo.w,
        eps1 * bf2f((u16)(hn.z & 0xFFFF)) + aHi.x,
        eps1 * bf2f((u16)(hn.z >> 16))    + aHi.y,
        eps1 * bf2f((u16)(hn.w & 0xFFFF)) + aHi.z,
        eps1 * bf2f((u16)(hn.w >> 16))    + aHi.w);
    *(uint4*)(z + (size_t)n * 256 + c8) = o;
  }
}

// ---------------- agg (W=448, layer 0): lane owns 8 cols, 56 live lanes --------
__global__ __launch_bounds__(256) void agg_z448(
    const u16* __restrict__ h, const float* __restrict__ etab,
    const int* __restrict__ ro, const int* __restrict__ csr,
    const float* __restrict__ epsp, u16* __restrict__ z, int N) {
  int wid = threadIdx.x >> 6, lane = threadIdx.x & 63;
  int n = blockIdx.x * 4 + wid;
  if (n >= N) return;
  int s0 = ro[n], s1 = ro[n + 1];
  float eps1 = 1.0f + *epsp;
  bool live = lane < 56;
  int c8 = live ? lane * 8 : 440;    // clamp dead lanes to a harmless chunk
  uint4 hn = *(const uint4*)(h + (size_t)n * W0 + c8);    // issued early
  float4 aLo = {0, 0, 0, 0}, aHi = {0, 0, 0, 0};

  for (int base = s0; base < s1; base += 64) {
    int m = s1 - base; if (m > 64) m = 64;
    int pk = (lane < m) ? csr[base + lane] : 0;
    int j = 0;
    for (; j + 1 < m; j += 2) {
      int p0 = __shfl(pk, j);
      int p1 = __shfl(pk, j + 1);
      uint4 h0v = *(const uint4*)(h + (size_t)(p0 & 0xFFFFF) * W0 + c8);
      uint4 h1v = *(const uint4*)(h + (size_t)(p1 & 0xFFFFF) * W0 + c8);
      const float* e0p = etab + (size_t)(p0 >> 20) * W0 + c8;
      const float* e1p = etab + (size_t)(p1 >> 20) * W0 + c8;
      float4 e0a = *(const float4*)e0p, e0b = *(const float4*)(e0p + 4);
      float4 e1a = *(const float4*)e1p, e1b = *(const float4*)(e1p + 4);
      acc8(aLo, aHi, h0v, e0a, e0b);
      acc8(aLo, aHi, h1v, e1a, e1b);
    }
    if (j < m) {
      int p = __shfl(pk, j);
      uint4 hv = *(const uint4*)(h + (size_t)(p & 0xFFFFF) * W0 + c8);
      const float* ep = etab + (size_t)(p >> 20) * W0 + c8;
      float4 ea = *(const float4*)ep, eb = *(const float4*)(ep + 4);
      acc8(aLo, aHi, hv, ea, eb);
    }
  }
  if (live) {
    uint4 o = pack8(
        eps1 * bf2f((u16)(hn.x & 0xFFFF)) + aLo.x,
        eps1 * bf2f((u16)(hn.x >> 16))    + aLo.y,
        eps1 * bf2f((u16)(hn.y & 0xFFFF)) + aLo.z,
        eps1 * bf2f((u16)(hn.y >> 16))    + aLo.w,
        eps1 * bf2f((u16)(hn.z & 0xFFFF)) + aHi.x,
        eps1 * bf2f((u16)(hn.z >> 16))    + aHi.y,
        eps1 * bf2f((u16)(hn.w & 0xFFFF)) + aHi.z,
        eps1 * bf2f((u16)(hn.w >> 16))    + aHi.w);
    *(uint4*)(z + (size_t)n * W0 + c8) = o;
  }
}

// ---------------- fused 2-stage MLP: C = silu(BN(silu(A@W1+b1)@W2+b2)) ---------
// Round-8/10 verified config: 128x256 tile, 256 thr / 4 waves (2x2 grid), 64KB
// LDS, launch_bounds(256,2) (no reg-cap spill), K=32 dbuf staging, frag-major W2.
__device__ __forceinline__ void g2l16(const u16* g, u16* l) {
  __builtin_amdgcn_global_load_lds(
      (__attribute__((address_space(1))) u32*)g,
      (__attribute__((address_space(3))) u32*)l, 16, 0, 0);
}

__global__ __launch_bounds__(256, 2) void layer_mlp(
    const u16* __restrict__ A, const u16* __restrict__ B1T,
    const float* __restrict__ b1v,
    const u16* __restrict__ B2F, const float* __restrict__ b2v,
    const float* __restrict__ gamma, const float* __restrict__ beta,
    u16* __restrict__ C, int M, int K1) {
  __shared__ __align__(16) u16 smem[32768];   // 64 KB: dbuf staging 2x24KB / U 64KB
  int tid = threadIdx.x;
  int wid = tid >> 6, lane = tid & 63;
  int q = lane >> 4, rr = lane & 15;
  int wm = wid >> 1, wn = wid & 1;          // 2x2 wave grid
  int m0 = blockIdx.x * 128;
  int lr2 = lane >> 2;                      // row within a 16-row DMA group
  int swz2 = (lane & 3) ^ ((lr2 >> 1) & 3); // swizzled 16B k-chunk this lane fetches

  f32x4 acc[4][8] = {};
  const int nk = K1 >> 5;                   // K-step = 32

  // ---- prologue: stage K-step 0 into buf0 ----
#pragma unroll
  for (int p = 0; p < 2; ++p) {             // A: 128 rows -> 8 groups of 16
    int g = wid * 2 + p;
    int gr = m0 + g * 16 + lr2; if (gr >= M) gr = M - 1;
    g2l16(A + (size_t)gr * K1 + swz2 * 8, smem + g * 512);
  }
#pragma unroll
  for (int p = 0; p < 4; ++p) {             // B: 256 rows -> 16 groups of 16
    int g = wid * 4 + p;
    g2l16(B1T + (size_t)(g * 16 + lr2) * K1 + swz2 * 8, smem + 4096 + g * 512);
  }
  __syncthreads();

  // ---- stage 1 main loop: stage(next) || compute(cur) ----
  for (int k = 0; k < nk; ++k) {
    int cur = (k & 1) * 12288;
    if (k + 1 < nk) {
      int nxt = 12288 - cur;
      int k0 = (k + 1) << 5;
#pragma unroll
      for (int p = 0; p < 2; ++p) {
        int g = wid * 2 + p;
        int gr = m0 + g * 16 + lr2; if (gr >= M) gr = M - 1;
        g2l16(A + (size_t)gr * K1 + k0 + swz2 * 8, smem + nxt + g * 512);
      }
#pragma unroll
      for (int p = 0; p < 4; ++p) {
        int g = wid * 4 + p;
        g2l16(B1T + (size_t)(g * 16 + lr2) * K1 + k0 + swz2 * 8,
              smem + nxt + 4096 + g * 512);
      }
    }
    const u16* dA = smem + cur;             // 128 rows x 32 k
    const u16* dB = smem + cur + 4096;      // 256 rows x 32 k
    int slot = (q ^ ((rr >> 1) & 3)) << 3;  // matches write-side swz2 key
    bf16x8 af[4], bf[8];
#pragma unroll
    for (int mt = 0; mt < 4; ++mt)
      af[mt] = *(const bf16x8*)&dA[(wm * 64 + mt * 16 + rr) * 32 + slot];
#pragma unroll
    for (int nt = 0; nt < 8; ++nt)
      bf[nt] = *(const bf16x8*)&dB[(wn * 128 + nt * 16 + rr) * 32 + slot];
#pragma unroll
    for (int mt = 0; mt < 4; ++mt)
#pragma unroll
      for (int nt = 0; nt < 8; ++nt)
        acc[mt][nt] = __builtin_amdgcn_mfma_f32_16x16x32_bf16(af[mt], bf[nt], acc[mt][nt], 0, 0, 0);
    __syncthreads();
  }

  // ---- epilogue 1: U = silu(acc + b1) -> swizzled LDS [128][256] bf16 ----
  // element (row,col) lives at u16 index row*256 + (((col>>3)^(row&7))<<3)+(col&7)
#pragma unroll
  for (int nt = 0; nt < 8; ++nt) {
    int col = wn * 128 + nt * 16 + rr;
    float bb = b1v[col];
    int cc = col >> 3, cl = col & 7;
#pragma unroll
    for (int mt = 0; mt < 4; ++mt)
#pragma unroll
      for (int i = 0; i < 4; ++i) {
        int row = wm * 64 + mt * 16 + q * 4 + i;
        smem[row * 256 + ((cc ^ (row & 7)) << 3) + cl] =
            f2bf_hw(siluf(acc[mt][nt][i] + bb));
      }
  }
  __syncthreads();

  // ---- stage 2: acc = U[128x256] @ W2; U from LDS, W2 frag-major coalesced ----
#pragma unroll
  for (int mt = 0; mt < 4; ++mt)
#pragma unroll
    for (int nt = 0; nt < 8; ++nt)
      acc[mt][nt] = (f32x4){0.f, 0.f, 0.f, 0.f};
  const u16* bbase = B2F + ((size_t)wn << 15) + (lane << 3);
#pragma unroll 2
  for (int kk = 0; kk < 8; ++kk) {
    bf16x8 af[4], bf[8];
#pragma unroll
    for (int mt = 0; mt < 4; ++mt)
      af[mt] = *(const bf16x8*)&smem[(wm * 64 + mt * 16 + rr) * 256 +
                                     ((((kk << 2) | q) ^ (rr & 7)) << 3)];
#pragma unroll
    for (int nt = 0; nt < 8; ++nt)
      bf[nt] = *(const bf16x8*)(bbase + ((nt << 12) | (kk << 9)));
#pragma unroll
    for (int mt = 0; mt < 4; ++mt)
#pragma unroll
      for (int nt = 0; nt < 8; ++nt)
        acc[mt][nt] = __builtin_amdgcn_mfma_f32_16x16x32_bf16(af[mt], bf[nt], acc[mt][nt], 0, 0, 0);
  }
  __syncthreads();                          // all waves done reading U

  // ---- epilogue 2: bias/BN/SiLU -> per-wave 16KB LDS slice -> coalesced store
  u16* slice = smem + wid * 8192;
#pragma unroll
  for (int nt = 0; nt < 8; ++nt) {
    int c = wn * 128 + nt * 16 + rr;
    float b = b2v[c];
    float sc = gamma ? gamma[c] * 0.9999950000374997f : 1.0f;   // gamma/sqrt(1+1e-5)
    float sh = beta ? beta[c] : 0.0f;
#pragma unroll
    for (int mt = 0; mt < 4; ++mt)
#pragma unroll
      for (int i = 0; i < 4; ++i) {
        float y = (acc[mt][nt][i] + b) * sc + sh;
        slice[(mt * 16 + q * 4 + i) * 128 + nt * 16 + rr] = f2bf_hw(siluf(y));
      }
  }
  __syncthreads();
  int rbase = m0 + wm * 64;
  int cbase = wn * 128;
#pragma unroll
  for (int j = 0; j < 16; ++j) {
    int idx = j * 64 + lane;                // uint4 index in slice (1024 total)
    int rloc = idx >> 4;                    // 16 uint4 per 128-col row
    int c8 = (idx & 15) * 8;
    if (rbase + rloc < M)
      *(uint4*)(C + (size_t)(rbase + rloc) * 256 + cbase + c8) =
          *(const uint4*)(slice + rloc * 128 + c8);
  }
}

// ---------------- MFMA head GEMM: [N,256] @ [256,32] -> atom_out[N,16], P[N,8(5)]
__global__ __launch_bounds__(256) void head_gemm(
    const u16* __restrict__ A, const u16* __restrict__ WT,
    const float* __restrict__ atomB,
    float* __restrict__ atom_out, float* __restrict__ P, int M) {
  __shared__ __align__(16) u16 lA[128 * 32];
  __shared__ __align__(16) u16 lB[32 * 264];
  int tid = threadIdx.x;
  int wid = tid >> 6, lane = tid & 63;
  int q = lane >> 4, rr = lane & 15;
  int m0 = blockIdx.x * 128;

  for (int i = tid; i < 32 * 256; i += 256)
    lB[(i >> 8) * 264 + (i & 255)] = WT[i];

  f32x4 acc[2][2] = {};
  int arow = tid >> 2, acol = (tid & 3) * 8;

  for (int k0 = 0; k0 < 256; k0 += 32) {
#pragma unroll
    for (int p = 0; p < 2; ++p) {
      int gr = m0 + p * 64 + arow;
      if (gr >= M) gr = M - 1;
      g2l16(A + (size_t)gr * 256 + k0 + acol, &lA[p * 2048 + wid * 512]);
    }
    __syncthreads();
    bf16x8 af[2], bfr[2];
#pragma unroll
    for (int mt = 0; mt < 2; ++mt)
      af[mt] = *(const bf16x8*)&lA[(wid * 32 + mt * 16 + rr) * 32 + q * 8];
#pragma unroll
    for (int nt = 0; nt < 2; ++nt)
      bfr[nt] = *(const bf16x8*)&lB[(nt * 16 + rr) * 264 + k0 + q * 8];
#pragma unroll
    for (int mt = 0; mt < 2; ++mt)
#pragma unroll
      for (int nt = 0; nt < 2; ++nt)
        acc[mt][nt] = __builtin_amdgcn_mfma_f32_16x16x32_bf16(af[mt], bfr[nt], acc[mt][nt], 0, 0, 0);
    __syncthreads();
  }

#pragma unroll
  for (int nt = 0; nt < 2; ++nt) {
    int c = nt * 16 + rr;
    float bb = (c < 16) ? atomB[c] : 0.0f;
#pragma unroll
    for (int mt = 0; mt < 2; ++mt) {
      int rbase = m0 + wid * 32 + mt * 16 + q * 4;
#pragma unroll
      for (int r2 = 0; r2 < 4; ++r2) {
        int row = rbase + r2;
        if (row < M) {
          float v = acc[mt][nt][r2];
          if (c < 16) atom_out[(size_t)row * 16 + c] = v + bb;
          else if (c < 21) P[(size_t)row * 8 + (c - 16)] = v;
        }
      }
    }
  }
}

// ---------------- bond edge output: out[e] = P[src]+P[dst]+b -------------------
__global__ __launch_bounds__(256) void bond_edge(
    const float* __restrict__ P, const int* __restrict__ src,
    const int* __restrict__ dst, const float* __restrict__ b,
    float* __restrict__ out, int E) {
  __shared__ float so[256 * 5];
  int t = threadIdx.x;
  int e = blockIdx.x * 256 + t;
  float v0 = 0, v1 = 0, v2 = 0, v3 = 0, v4 = 0;
  if (e < E) {
    int s = src[e], d = dst[e];
    float4 ps = *(const float4*)(P + (size_t)s * 8);
    float  p4s = P[(size_t)s * 8 + 4];
    float4 pd = *(const float4*)(P + (size_t)d * 8);
    float  p4d = P[(size_t)d * 8 + 4];
    v0 = ps.x + pd.x + b[0];
    v1 = ps.y + pd.y + b[1];
    v2 = ps.z + pd.z + b[2];
    v3 = ps.w + pd.w + b[3];
    v4 = p4s + p4d + b[4];
  }
  so[t * 5 + 0] = v0; so[t * 5 + 1] = v1; so[t * 5 + 2] = v2;
  so[t * 5 + 3] = v3; so[t * 5 + 4] = v4;
  __syncthreads();
  size_t base = (size_t)blockIdx.x * 256 * 5;
  size_t lim = (size_t)E * 5;
  for (int i = t; i < 256 * 5; i += 256) {
    size_t g = base + i;
    if (g < lim) out[g] = so[i];
  }
}

// ---------------- host ---------------------------------------------------------
extern "C" void kernel_launch(void* const* d_in, const int* in_sizes, int n_in,
                              void* d_out, int out_size, void* d_ws, size_t ws_size,
                              hipStream_t stream) {
  const int*   x_noisy   = (const int*)d_in[0];
  const int*   nmaskobs  = (const int*)d_in[1];
  const int*   ea        = (const int*)d_in[2];
  const int*   em        = (const int*)d_in[3];
  const int*   eidx      = (const int*)d_in[4];
  const int*   tnode     = (const int*)d_in[5];
  const float* cvec      = (const float*)d_in[6];
  const int*   batch     = (const int*)d_in[7];
  const float* atom_emb  = (const float*)d_in[8];
  const float* bond_emb  = (const float*)d_in[9];
  const float* nmask_emb = (const float*)d_in[10];
  const float* emask_emb = (const float*)d_in[11];
  const float* t_W1      = (const float*)d_in[12];
  const float* t_b1      = (const float*)d_in[13];
  const float* t_W2      = (const float*)d_in[14];
  const float* t_b2      = (const float*)d_in[15];
  const float* cond_W    = (const float*)d_in[16];
  const float* cond_b    = (const float*)d_in[17];
  const float* edge_W1   = (const float*)d_in[18];
  const float* edge_b1   = (const float*)d_in[19];
  const float* edge_W2   = (const float*)d_in[20];
  const float* edge_b2   = (const float*)d_in[21];
  const float* e0_W      = (const float*)d_in[22];
  const float* conv0_W1  = (const float*)d_in[23];
  const float* conv0_b1  = (const float*)d_in[24];
  const float* conv0_W2  = (const float*)d_in[25];
  const float* conv0_b2  = (const float*)d_in[26];
  const float* conv0_eps = (const float*)d_in[27];
  const float* convs_W1  = (const float*)d_in[28];
  const float* convs_b1  = (const float*)d_in[29];
  const float* convs_W2  = (const float*)d_in[30];
  const float* convs_b2  = (const float*)d_in[31];
  const float* convs_eps = (const float*)d_in[32];
  const float* bn_gamma  = (const float*)d_in[33];
  const float* bn_beta   = (const float*)d_in[34];
  const float* atom_W    = (const float*)d_in[35];
  const float* atom_b    = (const float*)d_in[36];
  const float* bond_W    = (const float*)d_in[37];
  const float* bond_b    = (const float*)d_in[38];

  const int N = in_sizes[0];
  const int E = in_sizes[2];
  const int B = in_sizes[6] / 2;
  const int* srcp = eidx;
  const int* dstp = eidx + E;

  char* base = (char*)d_ws;
  size_t off = 0;
  auto alloc = [&](size_t bytes) -> char* {
    char* p = base + off;
    off = (off + bytes + 255) & ~(size_t)255;
    return p;
  };
  u16* h0   = (u16*)alloc((size_t)N * W0 * 2);     // reused as h [N,256] ping
  u16* z0   = (u16*)alloc((size_t)N * W0 * 2);     // reused as z [N,256]
  u16* w10t = (u16*)alloc((size_t)DM * W0 * 2);
  u16* w20t = (u16*)alloc((size_t)DM * DM * 2);    // frag-major
  u16* wc1t = (u16*)alloc((size_t)5 * DM * DM * 2);
  u16* wc2t = (u16*)alloc((size_t)5 * DM * DM * 2); // frag-major
  u16* wht  = (u16*)alloc((size_t)32 * DM * 2);
  float* ttab  = (float*)alloc((size_t)200 * DM * 4);
  float* cprojb= (float*)alloc((size_t)B * DM * 4);
  float* eftab = (float*)alloc((size_t)10 * DM * 4);
  float* e0tab = (float*)alloc((size_t)10 * W0 * 4);
  float* Pbuf  = (float*)alloc((size_t)N * 8 * 4);
  int* deg  = (int*)alloc((size_t)N * 4);
  int* ro   = (int*)alloc((size_t)(N + 1) * 4);
  int* cur  = (int*)alloc((size_t)N * 4);
  int* csr  = (int*)alloc((size_t)E * 4);
  int* bsum = (int*)alloc((size_t)256 * 4);
  (void)ws_size; (void)n_in; (void)out_size;

  u16* hbuf = h0;
  u16* zbuf = z0;
  float* atom_out = (float*)d_out;
  float* bond_out = atom_out + (size_t)N * 16;

  hipMemsetAsync(deg, 0, (size_t)N * 4, stream);

  // ---- setup launch 1: weights + tables (all independent) ----
  const int prep_tot = DM * W0 + 5 * DM * DM + DM * DM + 5 * DM * DM + 32 * DM;
  const int PN = (prep_tot + 255) / 256;
  const int CP = (B * DM + 255) / 256;
  setup_a<<<PN + 200 + CP + 10, 256, 0, stream>>>(
      conv0_W1, conv0_W2, convs_W1, convs_W2, atom_W, bond_W,
      w10t, w20t, wc1t, wc2t, wht,
      t_W1, t_b1, t_W2, t_b2, ttab,
      cvec, cond_W, cond_b, cprojb, B,
      bond_emb, emask_emb, edge_W1, edge_b1, edge_W2, edge_b2, eftab,
      PN, CP);

  // ---- setup launch 2: h0 (wave-per-node) + e0tab + deg (grid-stride) ----
  const int HB = 2048;
  const int DB = 256;
  setup_b<<<HB + 10 + DB, 256, 0, stream>>>(
      x_noisy, nmaskobs, tnode, batch, atom_emb, nmask_emb, ttab, cprojb, h0, N,
      eftab, e0_W, e0tab,
      dstp, deg, E, HB, DB);

  // ---- CSR chain ----
  const int nscan = (N + 255) / 256;
  scan1_kernel<<<nscan, 256, 0, stream>>>(deg, ro, bsum, N);
  scan2_kernel<<<1, 256, 0, stream>>>(bsum, nscan);
  scan3_kernel<<<nscan, 256, 0, stream>>>(ro, cur, bsum, N, E);
  fill_kernel<<<(E + 255) / 256, 256, 0, stream>>>(srcp, dstp, ea, em, cur, csr, E);

  const int ggrid = (N + 127) / 128;  // 128-row tiles, 391 blocks
  const int nagg = (N + 3) / 4;
  // layer 0
  agg_z448<<<nagg, 256, 0, stream>>>(h0, e0tab, ro, csr, conv0_eps, z0, N);
  layer_mlp<<<ggrid, 256, 0, stream>>>(z0, w10t, conv0_b1, w20t, conv0_b2,
                                       bn_gamma, bn_beta, hbuf, N, W0);
  // layers 1..5
  for (int i = 0; i < 5; ++i) {
    agg_z256<<<nagg, 256, 0, stream>>>(hbuf, eftab, ro, csr, convs_eps + i, zbuf, N);
    layer_mlp<<<ggrid, 256, 0, stream>>>(zbuf, wc1t + (size_t)i * DM * DM, convs_b1 + i * DM,
                                         wc2t + (size_t)i * DM * DM, convs_b2 + i * DM,
                                         bn_gamma + (i + 1) * DM, bn_beta + (i + 1) * DM,
                                         hbuf, N, DM);
  }
  // heads
  head_gemm<<<(N + 127) / 128, 256, 0, stream>>>(hbuf, wht, atom_b, atom_out, Pbuf, N);
  bond_edge<<<(E + 255) / 256, 256, 0, stream>>>(Pbuf, srcp, dstp, bond_b, bond_out, E);
}